// Round 1
// baseline (321.860 us; speedup 1.0000x reference)
//
#include <hip/hip_runtime.h>
#include <math.h>

#define BATCH 256
#define VOCAB 128000
#define V4 (VOCAB / 4)
#define NTHREADS 1024
#define NWAVES (NTHREADS / 64)

typedef float vfloat4 __attribute__((ext_vector_type(4)));

// Restructure rationale (vs previous 318µs kernel):
//  - Old phase 1 had a per-ELEMENT serial chain (fmax -> exp -> fma), ~25-30 cy
//    of latency per element per thread, 2 transcendentals inside the chain.
//    Counters showed VALUBusy 37% + HBM 34% -> latency-bound, not roofline.
//  - New phase 1: chunk(float4)-level online softmax. Chunk max + 4 exps are
//    independent work; only ONE short merge chain per 4 elements.
//  - Softmax max == greedy max (inv_t > 0), so one compare chain serves both.
//  - Gumbel argmax needs only sc+g (no M, no S) -> moved into phase 1; phase 2
//    is a pure stream: read logits (L3-warm), 1 exp, write probs.
//  - 2x manual unroll, two independent accumulator sets per phase -> 4 loads
//    in flight per wave, 2 parallel merge chains.
__global__ __launch_bounds__(NTHREADS) void sampler_kernel(
    const float* __restrict__ logits,
    const float* __restrict__ temps,
    const float* __restrict__ noise,
    float* __restrict__ out_tokens,
    float* __restrict__ out_probs)
{
    const int b    = blockIdx.x;
    const int tid  = threadIdx.x;
    const int wave = tid >> 6;
    const int lane = tid & 63;

    const float t      = temps[b];
    const float safe_t = (t == 0.0f) ? 1.0f : t;
    const float inv_t  = 1.0f / safe_t;

    const vfloat4* lg4 = (const vfloat4*)(logits + (size_t)b * VOCAB);
    const vfloat4* nz4 = (const vfloat4*)(noise  + (size_t)b * VOCAB);
    vfloat4*       pb4 = (vfloat4*)(out_probs + (size_t)b * VOCAB);

    // ---------------- Phase 1: one pass over logits + noise.
    // Running state per accumulator set:
    //   gv/gi : max raw logit + first argmax (greedy)   [also the softmax max]
    //   s     : sum of exp((x - gv) * inv_t)            [softmax denom, scaled]
    //   sv/si : max of (x*inv_t + gumbel) + first index [sample]
    float gv0 = -INFINITY, gv1 = -INFINITY;
    int   gi0 = 0,          gi1 = 0;
    float s0  = 0.0f,       s1  = 0.0f;
    float sv0 = -INFINITY,  sv1 = -INFINITY;
    int   si0 = 0,          si1 = 0;

    auto proc1 = [&](const vfloat4 x4, const vfloat4 u4, int idx0,
                     float& gv, int& gi, float& s, float& sv, int& si) {
        // chunk max + first-occurrence argmax (independent tree, no chain)
        float v01 = fmaxf(x4[0], x4[1]);
        int   i01 = (x4[1] > x4[0]) ? idx0 + 1 : idx0;
        float v23 = fmaxf(x4[2], x4[3]);
        int   i23 = (x4[3] > x4[2]) ? idx0 + 3 : idx0 + 2;
        float cm  = fmaxf(v01, v23);
        int   cmi = (v23 > v01) ? i23 : i01;

        // 4 independent exps relative to chunk max (exponents <= 0: no overflow
        // even for tiny t / huge inv_t)
        float e0 = __expf((x4[0] - cm) * inv_t);
        float e1 = __expf((x4[1] - cm) * inv_t);
        float e2 = __expf((x4[2] - cm) * inv_t);
        float e3 = __expf((x4[3] - cm) * inv_t);
        float cs = (e0 + e1) + (e2 + e3);

        // the ONLY loop-carried chain: one fmax + fma (+2 exps feeding it) per 4 elems
        float mn = fmaxf(gv, cm);
        s = s * __expf((gv - mn) * inv_t) + cs * __expf((cm - mn) * inv_t);
        if (cm > gv) gi = cmi;   // strict '>' keeps first index (chunk idx increases)
        gv = mn;

        // Gumbel-max: z = x*inv_t + (-log(-log(u))) -- same op order as reference
        float g0 = -__logf(-__logf(u4[0]));
        float g1 = -__logf(-__logf(u4[1]));
        float g2 = -__logf(-__logf(u4[2]));
        float g3 = -__logf(-__logf(u4[3]));
        float z0 = x4[0] * inv_t + g0;
        float z1 = x4[1] * inv_t + g1;
        float z2 = x4[2] * inv_t + g2;
        float z3 = x4[3] * inv_t + g3;
        float w01 = fmaxf(z0, z1);
        int   j01 = (z1 > z0) ? idx0 + 1 : idx0;
        float w23 = fmaxf(z2, z3);
        int   j23 = (z3 > z2) ? idx0 + 3 : idx0 + 2;
        float wm  = fmaxf(w01, w23);
        int   wmi = (w23 > w01) ? j23 : j01;
        if (wm > sv) { si = wmi; sv = wm; }   // one short chain per chunk
    };

    // 2x unrolled stream: 4 loads in flight per wave, two independent acc sets
    int i = tid;
    for (; i + NTHREADS < V4; i += 2 * NTHREADS) {
        vfloat4 xa = lg4[i];
        vfloat4 xb = lg4[i + NTHREADS];
        vfloat4 ua = __builtin_nontemporal_load(&nz4[i]);
        vfloat4 ub = __builtin_nontemporal_load(&nz4[i + NTHREADS]);
        proc1(xa, ua, 4 * i,              gv0, gi0, s0, sv0, si0);
        proc1(xb, ub, 4 * (i + NTHREADS), gv1, gi1, s1, sv1, si1);
    }
    if (i < V4) {
        vfloat4 xa = lg4[i];
        vfloat4 ua = __builtin_nontemporal_load(&nz4[i]);
        proc1(xa, ua, 4 * i, gv0, gi0, s0, sv0, si0);
    }

    // merge set1 into set0 (both sets processed >=15 chunks: all finite)
    {
        float mn = fmaxf(gv0, gv1);
        s0 = s0 * __expf((gv0 - mn) * inv_t) + s1 * __expf((gv1 - mn) * inv_t);
        if (gv1 > gv0 || (gv1 == gv0 && gi1 < gi0)) gi0 = gi1;
        gv0 = mn;
        if (sv1 > sv0 || (sv1 == sv0 && si1 < si0)) { sv0 = sv1; si0 = si1; }
    }

    // wave-level reduction (64 lanes)
#pragma unroll
    for (int off = 32; off >= 1; off >>= 1) {
        float gv2 = __shfl_down(gv0, off);
        int   gi2 = __shfl_down(gi0, off);
        float s2  = __shfl_down(s0,  off);
        float sv2 = __shfl_down(sv0, off);
        int   si2 = __shfl_down(si0, off);
        float mn = fmaxf(gv0, gv2);
        s0 = s0 * __expf((gv0 - mn) * inv_t) + s2 * __expf((gv2 - mn) * inv_t);
        if (gv2 > gv0 || (gv2 == gv0 && gi2 < gi0)) gi0 = gi2;
        gv0 = mn;
        if (sv2 > sv0 || (sv2 == sv0 && si2 < si0)) { sv0 = sv2; si0 = si2; }
    }

    __shared__ float sh_gv[NWAVES], sh_s[NWAVES], sh_sv[NWAVES];
    __shared__ int   sh_gi[NWAVES], sh_si[NWAVES];
    __shared__ float bGV, binvS;
    if (lane == 0) {
        sh_gv[wave] = gv0; sh_s[wave] = s0; sh_gi[wave] = gi0;
        sh_sv[wave] = sv0; sh_si[wave] = si0;
    }
    __syncthreads();
    if (tid == 0) {
        float GVr = sh_gv[0], S = sh_s[0], SV = sh_sv[0];
        int   GI  = sh_gi[0], SI = sh_si[0];
        for (int w = 1; w < NWAVES; ++w) {
            float mn = fmaxf(GVr, sh_gv[w]);
            S = S * __expf((GVr - mn) * inv_t) + sh_s[w] * __expf((sh_gv[w] - mn) * inv_t);
            if (sh_gv[w] > GVr || (sh_gv[w] == GVr && sh_gi[w] < GI)) GI = sh_gi[w];
            GVr = mn;
            if (sh_sv[w] > SV || (sh_sv[w] == SV && sh_si[w] < SI)) { SV = sh_sv[w]; SI = sh_si[w]; }
        }
        bGV = GVr; binvS = 1.0f / S;   // S >= 1 always (max element contributes 1)
        out_tokens[b] = (float)((t == 0.0f) ? GI : SI);
    }
    __syncthreads();
    const float Msc  = bGV * inv_t;   // softmax max in scaled domain
    const float invS = binvS;

    // ---------------- Phase 2: pure stream. logits re-read is L3-warm (noise
    // was nontemporal so logits stayed resident). 1 exp + 1 fma per element.
    int k = tid;
    for (; k + NTHREADS < V4; k += 2 * NTHREADS) {
        vfloat4 xa = lg4[k];
        vfloat4 xb = lg4[k + NTHREADS];
        vfloat4 pa, pb;
#pragma unroll
        for (int j = 0; j < 4; ++j)
            pa[j] = __expf(fmaf(xa[j], inv_t, -Msc)) * invS;
#pragma unroll
        for (int j = 0; j < 4; ++j)
            pb[j] = __expf(fmaf(xb[j], inv_t, -Msc)) * invS;
        __builtin_nontemporal_store(pa, &pb4[k]);
        __builtin_nontemporal_store(pb, &pb4[k + NTHREADS]);
    }
    if (k < V4) {
        vfloat4 xa = lg4[k];
        vfloat4 pa;
#pragma unroll
        for (int j = 0; j < 4; ++j)
            pa[j] = __expf(fmaf(xa[j], inv_t, -Msc)) * invS;
        __builtin_nontemporal_store(pa, &pb4[k]);
    }
}

extern "C" void kernel_launch(void* const* d_in, const int* in_sizes, int n_in,
                              void* d_out, int out_size, void* d_ws, size_t ws_size,
                              hipStream_t stream) {
    const float* logits = (const float*)d_in[0];
    const float* temps  = (const float*)d_in[1];
    const float* noise  = (const float*)d_in[2];
    float* out = (float*)d_out;
    // d_out layout: [tokens (BATCH floats)] [probs (BATCH*VOCAB floats)]
    sampler_kernel<<<BATCH, NTHREADS, 0, stream>>>(logits, temps, noise,
                                                   out, out + BATCH);
}